// Round 3
// baseline (289.437 us; speedup 1.0000x reference)
//
#include <hip/hip_runtime.h>

#define NC 14
#define DIM 96
#define PP (DIM*DIM*DIM)       // 884736 voxels per batch
#define BLOCKS_PER_B 3456      // 221184 quads/batch / 64 quads-per-block

// Team-of-4 design: each 4-lane team handles one quad (4 consecutive d voxels).
// Lane j loads classes {j, 4+j, 8+j, 12+(j&1)} (4th weighted 0 for j>=2) ->
// 8 independent float4 loads per lane (single waitcnt group), then shfl_xor
// butterfly over the team to combine per-voxel softmax partials.
__global__ __launch_bounds__(256) void bkd_main(
    const float* __restrict__ S, const float* __restrict__ T,
    const int* __restrict__ lab,
    double* __restrict__ gnum, int* __restrict__ gcnt)
{
    const int tid = threadIdx.x;
    const int j   = tid & 3;                              // team lane
    const unsigned bq = blockIdx.x;
    const unsigned b  = bq / BLOCKS_PER_B;                // 0 or 1 (block-uniform)
    const unsigned qi = (bq - b * BLOCKS_PER_B) * 64u + (unsigned)(tid >> 2);
    const int p = (int)(qi * 4u);                         // quad base voxel
    const int d = p % DIM;
    const int t = p / DIM;
    const int w = t % DIM;
    const int h = t / DIM;

    // ---- S/T loads: 8 independent float4 per lane ----
    const float* Tb = T + (size_t)b * NC * PP + p;
    const float* Sb = S + (size_t)b * NC * PP + p;
    const int cD = 12 + (j & 1);                          // valid addr even for j>=2
    const float w4 = (j < 2) ? 1.f : 0.f;                 // 4th class weight
    const float4 tA = *(const float4*)(Tb + (size_t)(j)      * PP);
    const float4 sA = *(const float4*)(Sb + (size_t)(j)      * PP);
    const float4 tB = *(const float4*)(Tb + (size_t)(4 + j)  * PP);
    const float4 sB = *(const float4*)(Sb + (size_t)(4 + j)  * PP);
    const float4 tC = *(const float4*)(Tb + (size_t)(8 + j)  * PP);
    const float4 sC = *(const float4*)(Sb + (size_t)(8 + j)  * PP);
    const float4 tD = *(const float4*)(Tb + (size_t)cD       * PP);
    const float4 sD = *(const float4*)(Sb + (size_t)cD       * PP);

    float ZT0=0,ZT1=0,ZT2=0,ZT3=0, ZS0=0,ZS1=0,ZS2=0,ZS3=0, A0=0,A1=0,A2=0,A3=0;
#define ACC(t4, s4, wgt)                                                     \
    {                                                                        \
        const float u0 = __expf(t4.x) * (wgt), u1 = __expf(t4.y) * (wgt),    \
                    u2 = __expf(t4.z) * (wgt), u3 = __expf(t4.w) * (wgt);    \
        ZT0 += u0; ZT1 += u1; ZT2 += u2; ZT3 += u3;                          \
        ZS0 += __expf(s4.x) * (wgt); ZS1 += __expf(s4.y) * (wgt);            \
        ZS2 += __expf(s4.z) * (wgt); ZS3 += __expf(s4.w) * (wgt);            \
        A0 = fmaf(u0, t4.x - s4.x, A0); A1 = fmaf(u1, t4.y - s4.y, A1);      \
        A2 = fmaf(u2, t4.z - s4.z, A2); A3 = fmaf(u3, t4.w - s4.w, A3);      \
    }
    ACC(tA, sA, 1.f) ACC(tB, sB, 1.f) ACC(tC, sC, 1.f) ACC(tD, sD, w4)
#undef ACC

    // ---- team butterfly (4 lanes): full per-voxel sums on every lane ----
#define BFLY(v) v += __shfl_xor(v, 1, 64); v += __shfl_xor(v, 2, 64);
    BFLY(ZT0) BFLY(ZT1) BFLY(ZT2) BFLY(ZT3)
    BFLY(ZS0) BFLY(ZS1) BFLY(ZS2) BFLY(ZS3)
    BFLY(A0)  BFLY(A1)  BFLY(A2)  BFLY(A3)
#undef BFLY

    // lane j owns voxel j of the quad
    const float Aj  = (j == 0) ? A0  : (j == 1) ? A1  : (j == 2) ? A2  : A3;
    const float ZTj = (j == 0) ? ZT0 : (j == 1) ? ZT1 : (j == 2) ? ZT2 : ZT3;
    const float ZSj = (j == 0) ? ZS0 : (j == 1) ? ZS1 : (j == 2) ? ZS2 : ZS3;
    const float kl  = Aj / ZTj + __logf(ZSj) - __logf(ZTj);

    // ---- labels: 9 neighbor rows split across team: {0,4},{1,5},{2,6},{3,7,8} ----
    const int lbase = (int)b * PP;
    unsigned m0 = 0, m1 = 0, m2 = 0, m3 = 0;
#define DOROW(rw)                                                            \
    {                                                                        \
        const int dh = (rw) / 3 - 1, dw = (rw) % 3 - 1;                      \
        const int hh = h + dh, ww = w + dw;                                  \
        if ((unsigned)hh < (unsigned)DIM && (unsigned)ww < (unsigned)DIM) {  \
            const int* rp = lab + lbase + (hh * DIM + ww) * DIM + d;         \
            const int4 v = *(const int4*)rp;                                 \
            const unsigned a0 = 1u << v.x, a1 = 1u << v.y,                   \
                           a2 = 1u << v.z, a3 = 1u << v.w;                   \
            const unsigned mla = (d > 0)       ? (1u << rp[-1]) : 0u;        \
            const unsigned mlb = (d < DIM - 4) ? (1u << rp[4])  : 0u;        \
            if ((rw) == 4) {                                                 \
                m0 |= mla | a1; m1 |= a0 | a2; m2 |= a1 | a3; m3 |= a2 | mlb;\
            } else {                                                         \
                const unsigned s01 = a0|a1, s12 = a1|a2, s23 = a2|a3;        \
                m0 |= mla|s01; m1 |= s01|a2; m2 |= s12|a3; m3 |= s23|mlb;    \
            }                                                                \
        }                                                                    \
    }
    DOROW(j)
    DOROW(j + 4)
    if (j == 3) DOROW(8)
#undef DOROW

    // OR-combine masks across the team
#define BOR(m) m |= __shfl_xor(m, 1, 64); m |= __shfl_xor(m, 2, 64);
    BOR(m0) BOR(m1) BOR(m2) BOR(m3)
#undef BOR

    // interior single-class voxels contribute nothing
    const bool hwi = (h >= 1 && h <= DIM - 2 && w >= 1 && w <= DIM - 2);
    const bool din = (j == 0) ? (d > 0) : (j == 3) ? (d < DIM - 4) : true;
    unsigned mj = (j == 0) ? m0 : (j == 1) ? m1 : (j == 2) ? m2 : m3;
    if (hwi && din && (mj & (mj - 1)) == 0) mj = 0;

    // ---- reduce: counts via ballot, nums via 64-lane butterfly ----
    __shared__ float s_num[NC];
    __shared__ int   s_cnt[NC];
    if (tid < NC) { s_num[tid] = 0.f; s_cnt[tid] = 0; }
    __syncthreads();

    const int lane0 = ((tid & 63) == 0);
#pragma unroll
    for (int k = 0; k < NC; ++k) {
        const unsigned bit = 1u << k;
        const unsigned long long bal = __ballot(mj & bit);
        float v = (mj & bit) ? kl : 0.f;
#pragma unroll
        for (int off = 32; off > 0; off >>= 1)
            v += __shfl_xor(v, off, 64);
        if (lane0) {
            atomicAdd(&s_num[k], v);
            atomicAdd(&s_cnt[k], (int)__popcll(bal));
        }
    }
    __syncthreads();
    if (tid < NC) {
        atomicAdd(&gnum[b * NC + tid], (double)s_num[tid]);
        atomicAdd(&gcnt[b * NC + tid], s_cnt[tid]);
    }
}

__global__ void bkd_final(const double* __restrict__ gnum,
                          const int* __restrict__ gcnt,
                          float* __restrict__ out)
{
    const int i = threadIdx.x;            // one block of 64 threads
    double term = 0.0;
    if (i < 2 * NC) {
        const int c = gcnt[i];
        if (c > 0) term = gnum[i] / ((double)NC * (double)c);
    }
#pragma unroll
    for (int off = 32; off > 0; off >>= 1)
        term += __shfl_down(term, off, 64);
    if (i == 0) out[0] = (float)term;
}

extern "C" void kernel_launch(void* const* d_in, const int* in_sizes, int n_in,
                              void* d_out, int out_size, void* d_ws, size_t ws_size,
                              hipStream_t stream) {
    const float* S  = (const float*)d_in[0];   // preds_S [2,14,96,96,96] f32
    const float* T  = (const float*)d_in[1];   // preds_T [2,14,96,96,96] f32
    const int* lab  = (const int*)d_in[2];     // gt_labels [2,1,96,96,96] int32
    float* out      = (float*)d_out;

    double* gnum = (double*)d_ws;                                   // [2*14]
    int*    gcnt = (int*)((char*)d_ws + 2 * NC * sizeof(double));   // [2*14]

    hipMemsetAsync(d_ws, 0, 2 * NC * (sizeof(double) + sizeof(int)), stream);

    bkd_main<<<2 * BLOCKS_PER_B, 256, 0, stream>>>(S, T, lab, gnum, gcnt);
    bkd_final<<<1, 64, 0, stream>>>(gnum, gcnt, out);
}